// Round 7
// baseline (2800.148 us; speedup 1.0000x reference)
//
#include <hip/hip_runtime.h>

typedef unsigned short u16;
typedef unsigned long long u64;
typedef short bf16x8 __attribute__((ext_vector_type(8)));
typedef float f32x4 __attribute__((ext_vector_type(4)));

#define B_ 256
#define T_ 512
#define I_ 64
#define H_ 512
#define RING 32

// ---------------- ws layout (bytes) ---------------- (identical to R4/R6)
#define OFF_F0    0u
#define OFF_F1    32768u
#define OFF_F2    65536u
#define OFF_F3    98304u
#define OFF_B0    131072u
#define OFF_B1    139264u
#define OFF_WIH0  147456u
#define OFF_WHH0  409600u
#define OFF_WIH1  2506752u
#define OFF_WHH1  4603904u
#define OFF_HX1   6701056u
#define OFF_H1R   7225344u
#define WS_NEEDED 15613952u

#define AQ __ATOMIC_RELAXED
#define SC __HIP_MEMORY_SCOPE_AGENT

static __device__ __forceinline__ u16 f2b(float f) {
  union { float f; unsigned u; } v; v.f = f;
  unsigned r = (v.u + 0x7FFFu + ((v.u >> 16) & 1u)) >> 16;
  return (u16)r;
}
static __device__ __forceinline__ float sigm(float x) { return 1.f / (1.f + __expf(-x)); }
static __device__ __forceinline__ float tanh_(float x) { return 1.f - 2.f / (__expf(2.f * x) + 1.f); }

// pipelined spin: 2 outstanding flag loads -> sampling period ~RTT/2
static __device__ __forceinline__ void spin2(const unsigned* __restrict__ pa, unsigned tg) {
  unsigned a = __hip_atomic_load(pa, AQ, SC);
  for (;;) {
    unsigned b = __hip_atomic_load(pa, AQ, SC);
    if (!__any(a < tg)) break;
    a = __hip_atomic_load(pa, AQ, SC);
    if (!__any(b < tg)) break;
  }
}

// ---------------- prep: bf16 weights, bias sums, flag zero, out=bfc ----------------
__global__ void prep_kernel(const float* __restrict__ Wih0, const float* __restrict__ Whh0,
                            const float* __restrict__ bih0, const float* __restrict__ bhh0,
                            const float* __restrict__ Wih1, const float* __restrict__ Whh1,
                            const float* __restrict__ bih1, const float* __restrict__ bhh1,
                            const float* __restrict__ bfc, float* __restrict__ out,
                            char* __restrict__ ws) {
  unsigned* flags = (unsigned*)(ws + OFF_F0);
  float* b0 = (float*)(ws + OFF_B0);
  float* b1 = (float*)(ws + OFF_B1);
  u16* wih0b = (u16*)(ws + OFF_WIH0);
  u16* whh0b = (u16*)(ws + OFF_WHH0);
  u16* wih1b = (u16*)(ws + OFF_WIH1);
  u16* whh1b = (u16*)(ws + OFF_WHH1);

  long long i = (long long)blockIdx.x * 256 + threadIdx.x;
  if (i < 32768) { __hip_atomic_store(&flags[i], 0u, AQ, SC); return; }
  i -= 32768;
  if (i < 256) { out[i] = bfc[0]; return; }
  i -= 256;
  if (i < 2048) { b0[i] = bih0[i] + bhh0[i]; return; }
  i -= 2048;
  if (i < 2048) { b1[i] = bih1[i] + bhh1[i]; return; }
  i -= 2048;
  if (i < 131072) { wih0b[i] = f2b(Wih0[i]); return; }
  i -= 131072;
  if (i < 1048576) { whh0b[i] = f2b(Whh0[i]); return; }
  i -= 1048576;
  if (i < 1048576) { wih1b[i] = f2b(Wih1[i]); return; }
  i -= 1048576;
  if (i < 1048576) { whh1b[i] = f2b(Whh1[i]); return; }
}

// ---------------- fused 2-layer pipelined LSTM (R6 + XCD-clustered + no barC) --------
// XCD clustering: bx -> (ib = bx&7, jn = bx>>3) so the whole clique for batch-group ib
// (32 L0 + 32 L1 blocks, all its flag lines + ring/hx rows) lands on XCD bx%8 = ib.
// Per step: [input GEMM] -> wave0 dual-spin -> barA -> setprio1 -> rec GEMM ->
// vec dump (col-major Gp, DOUBLE-buffered) -> barB -> elemwise + h store -> setprio0 ->
// per-wave vmcnt(0) drain -> waves1-3 post LDS done-flag; wave0 gathers flags and
// scatters the block-granular signal (no third barrier; waves1-3 start t+1 early).
template <bool IS_L0>
__device__ __forceinline__ void lstm_body(
    int ib, int jn,
    const float* __restrict__ x,
    const u16* __restrict__ Wib,
    const u16* __restrict__ Whb,
    const float* __restrict__ bias,
    unsigned* __restrict__ hx32,
    u16* __restrict__ h1ring,
    const float* __restrict__ Wfc, float* __restrict__ out,
    unsigned* __restrict__ fR,
    unsigned* __restrict__ fP,
    unsigned* __restrict__ fC,
    float* __restrict__ Gp_s,         // [2][64 cols][132 rows] f32 (col-major, padded)
    unsigned* __restrict__ done_s)    // [4] per-wave drain flags (LDS)
{
  const int tid = threadIdx.x;
  const int wv = tid >> 6;
  const int lane = tid & 63;
  const int quad = lane >> 4;
  const int l15 = lane & 15;

  bf16x8 Bh[4][4];
#pragma unroll
  for (int r = 0; r < 4; ++r)
#pragma unroll
    for (int nt = 0; nt < 4; ++nt)
      Bh[r][nt] = *(const bf16x8*)&Whb[(size_t)(nt * 512 + jn * 16 + l15) * 512 +
                                       (wv * 4 + r) * 32 + quad * 8];
  bf16x8 Bx[4][4];
  bf16x8 Bx0[4];
  if constexpr (IS_L0) {
    if (wv < 2) {
#pragma unroll
      for (int nt = 0; nt < 4; ++nt)
        Bx0[nt] = *(const bf16x8*)&Wib[(size_t)(nt * 512 + jn * 16 + l15) * 64 +
                                       wv * 32 + quad * 8];
    }
  } else {
#pragma unroll
    for (int r = 0; r < 4; ++r)
#pragma unroll
      for (int nt = 0; nt < 4; ++nt)
        Bx[r][nt] = *(const bf16x8*)&Wib[(size_t)(nt * 512 + jn * 16 + l15) * 512 +
                                         (wv * 4 + r) * 32 + quad * 8];
  }

  const int erow = tid >> 3;
  const int ecp = tid & 7;
  float bias2[4][2];
#pragma unroll
  for (int g = 0; g < 4; ++g) {
    bias2[g][0] = bias[g * 512 + jn * 16 + 2 * ecp];
    bias2[g][1] = bias[g * 512 + jn * 16 + 2 * ecp + 1];
  }
  float cst2[2] = {0.f, 0.f};
  const f32x4 zf = {0.f, 0.f, 0.f, 0.f};
  const unsigned lineoff = ((unsigned)ib * 32 + jn) * 32;

  const int bg = ib * 32 + erow;
  const int hg = jn * 16 + 2 * ecp;
  const unsigned stoff = (unsigned)(((hg >> 3) * 256 + bg) * 4 + (ecp & 3));

  const unsigned* pollP;
  if constexpr (IS_L0)
    pollP = (lane < 32) ? &fR[lineoff + lane] : &fC[lineoff + (lane - 32)];
  else
    pollP = (lane < 32) ? &fR[lineoff + lane] : &fP[lineoff + (lane - 32)];

  if constexpr (!IS_L0) {
    // pre-loop: confirm fP >= 1 so iteration 0's input GEMM may read ring slot 0
    if (wv == 0) spin2(&fP[lineoff + (lane & 31)], 1u);
    __syncthreads();
  }

  for (int t = 0; t < T_; ++t) {
    f32x4 acc[2][4];
#pragma unroll
    for (int mt = 0; mt < 2; ++mt)
#pragma unroll
      for (int nt = 0; nt < 4; ++nt) acc[mt][nt] = zf;

    if constexpr (IS_L0) {
      // x(t) -> regs; input GEMM before the poll (h-independent)
      if (wv < 2) {
        const float* xp = x + ((size_t)(ib * 32 + l15) * T_ + t) * 64 + wv * 32 + quad * 8;
        const float* xq = xp + (size_t)16 * T_ * 64;
        float4 xa = *(const float4*)xp;
        float4 xb = *(const float4*)(xp + 4);
        float4 xc = *(const float4*)xq;
        float4 xd = *(const float4*)(xq + 4);
        union { unsigned u[4]; bf16x8 v; } P0, P1;
        P0.u[0] = (unsigned)f2b(xa.x) | ((unsigned)f2b(xa.y) << 16);
        P0.u[1] = (unsigned)f2b(xa.z) | ((unsigned)f2b(xa.w) << 16);
        P0.u[2] = (unsigned)f2b(xb.x) | ((unsigned)f2b(xb.y) << 16);
        P0.u[3] = (unsigned)f2b(xb.z) | ((unsigned)f2b(xb.w) << 16);
        P1.u[0] = (unsigned)f2b(xc.x) | ((unsigned)f2b(xc.y) << 16);
        P1.u[1] = (unsigned)f2b(xc.z) | ((unsigned)f2b(xc.w) << 16);
        P1.u[2] = (unsigned)f2b(xd.x) | ((unsigned)f2b(xd.y) << 16);
        P1.u[3] = (unsigned)f2b(xd.z) | ((unsigned)f2b(xd.w) << 16);
#pragma unroll
        for (int nt = 0; nt < 4; ++nt) {
          acc[0][nt] = __builtin_amdgcn_mfma_f32_16x16x32_bf16(P0.v, Bx0[nt], acc[0][nt], 0, 0, 0);
          acc[1][nt] = __builtin_amdgcn_mfma_f32_16x16x32_bf16(P1.v, Bx0[nt], acc[1][nt], 0, 0, 0);
        }
      }
      // wave0 dual-spin: fR >= t ; fC >= t-RING+1
      if (t && wv == 0) {
        const unsigned tg = (lane < 32) ? (unsigned)t
                            : ((t >= RING) ? (unsigned)(t - RING + 1) : 0u);
        spin2(pollP, tg);
      }
      __syncthreads();   // barA
    } else {
      // input GEMM from ring slot t (validity: fP>=t+1 confirmed by prev iter's spin)
      const u64* hq1 = (const u64*)h1ring + (size_t)(t & (RING - 1)) * (B_ * H_ / 4);
#pragma unroll
      for (int r = 0; r < 4; ++r) {
        int ks = wv * 4 + r;
        bf16x8 af[2];
#pragma unroll
        for (int mt = 0; mt < 2; ++mt) {
          const u64* p = hq1 + (size_t)((ks * 4 + quad) * 256 + ib * 32 + mt * 16 + l15) * 2;
          union { u64 q[2]; bf16x8 v; } u;
          u.q[0] = __hip_atomic_load(p, AQ, SC);
          u.q[1] = __hip_atomic_load(p + 1, AQ, SC);
          af[mt] = u.v;
        }
#pragma unroll
        for (int nt = 0; nt < 4; ++nt) {
          acc[0][nt] = __builtin_amdgcn_mfma_f32_16x16x32_bf16(af[0], Bx[r][nt], acc[0][nt], 0, 0, 0);
          acc[1][nt] = __builtin_amdgcn_mfma_f32_16x16x32_bf16(af[1], Bx[r][nt], acc[1][nt], 0, 0, 0);
        }
      }
      // wave0 dual-spin: fR >= t ; fP >= min(t+2, T) (prefetch next step's input validity)
      if (wv == 0) {
        unsigned tP = (unsigned)(t + 2); if (tP > (unsigned)T_) tP = (unsigned)T_;
        const unsigned tg = (lane < 32) ? (unsigned)t : tP;
        spin2(pollP, tg);
      }
      __syncthreads();   // barA
    }

    __builtin_amdgcn_s_setprio(1);

    // ---- recurrent GEMM: L0 reads ring slot (t-1)&31, L1 its parity buffer
    if (t) {
      const u64* hq;
      if constexpr (IS_L0)
        hq = (const u64*)h1ring + (size_t)((t - 1) & (RING - 1)) * (B_ * H_ / 4);
      else
        hq = (const u64*)hx32 + (size_t)(t & 1) * (B_ * H_ / 4);
      bf16x8 af[4][2];
#pragma unroll
      for (int r = 0; r < 4; ++r) {
        int ks = wv * 4 + r;
#pragma unroll
        for (int mt = 0; mt < 2; ++mt) {
          const u64* p = hq + (size_t)((ks * 4 + quad) * 256 + ib * 32 + mt * 16 + l15) * 2;
          union { u64 q[2]; bf16x8 v; } u;
          u.q[0] = __hip_atomic_load(p, AQ, SC);
          u.q[1] = __hip_atomic_load(p + 1, AQ, SC);
          af[r][mt] = u.v;
        }
      }
#pragma unroll
      for (int r = 0; r < 4; ++r)
#pragma unroll
        for (int mt = 0; mt < 2; ++mt)
#pragma unroll
          for (int nt = 0; nt < 4; ++nt)
            acc[mt][nt] = __builtin_amdgcn_mfma_f32_16x16x32_bf16(af[r][mt], Bh[r][nt],
                                                                  acc[mt][nt], 0, 0, 0);
    }

    // ---- vectorized dump into DOUBLE-buffered col-major Gp[2][64 cols][132 rows]
    float* __restrict__ Gp = Gp_s + (t & 1) * (64 * 132);
#pragma unroll
    for (int mt = 0; mt < 2; ++mt)
#pragma unroll
      for (int nt = 0; nt < 4; ++nt)
        *(f32x4*)&Gp[(nt * 16 + l15) * 132 + wv * 32 + mt * 16 + quad * 4] = acc[mt][nt];
    __syncthreads();   // barB

    // ---- elemwise: reduce partials (col-major reads), gates, c/h, store h
    {
      float pre[4][2];
#pragma unroll
      for (int g = 0; g < 4; ++g) {
#pragma unroll
        for (int j = 0; j < 2; ++j) {
          const int c = g * 16 + 2 * ecp + j;
          float s = bias2[g][j];
#pragma unroll
          for (int w = 0; w < 4; ++w) s += Gp[c * 132 + w * 32 + erow];
          pre[g][j] = s;
        }
      }
      float hv[2];
#pragma unroll
      for (int j = 0; j < 2; ++j) {
        float iv = sigm(pre[0][j]);
        float fv = sigm(pre[1][j]);
        float gv = tanh_(pre[2][j]);
        float ov = sigm(pre[3][j]);
        float cn = fv * cst2[j] + iv * gv;
        cst2[j] = cn;
        hv[j] = ov * tanh_(cn);
      }
      unsigned pack = (unsigned)f2b(hv[0]) | ((unsigned)f2b(hv[1]) << 16);
      if constexpr (IS_L0) {
        unsigned* ring32 = (unsigned*)h1ring;
        __hip_atomic_store(&ring32[(size_t)(t & (RING - 1)) * (B_ * H_ / 2) + stoff],
                           pack, AQ, SC);
      } else {
        __hip_atomic_store(&hx32[(size_t)((t + 1) & 1) * (B_ * H_ / 2) + stoff], pack, AQ, SC);
        if (t == T_ - 1) {
          float part = hv[0] * Wfc[hg] + hv[1] * Wfc[hg + 1];
          part += __shfl_down(part, 4, 8);
          part += __shfl_down(part, 2, 8);
          part += __shfl_down(part, 1, 8);
          if (ecp == 0) atomicAdd(&out[bg], part);
        }
      }
    }
    __builtin_amdgcn_s_setprio(0);

    // ---- per-wave drain; waves1-3 post LDS done and run ahead; wave0 gathers + signals
    asm volatile("s_waitcnt vmcnt(0)" ::: "memory");
    if (wv) {
      if (lane == 0)
        __hip_atomic_store(&done_s[wv], (unsigned)(t + 1), __ATOMIC_RELEASE,
                           __HIP_MEMORY_SCOPE_WORKGROUP);
    } else {
      const int di = (lane & 3) ? (lane & 3) : 1;
      unsigned dv;
      do {
        dv = __hip_atomic_load(&done_s[di], __ATOMIC_ACQUIRE, __HIP_MEMORY_SCOPE_WORKGROUP);
      } while (__any(dv < (unsigned)(t + 1)));
      const unsigned val = (unsigned)(t + 1);
      if constexpr (IS_L0) {
        if (lane < 32)
          __hip_atomic_store(&fR[((unsigned)ib * 32 + lane) * 32 + jn], val, AQ, SC);
        else
          __hip_atomic_store(&fP[((unsigned)ib * 32 + (lane - 32)) * 32 + jn], val, AQ, SC);
      } else {
        if (lane < 32)
          __hip_atomic_store(&fR[((unsigned)ib * 32 + lane) * 32 + jn], val, AQ, SC);
        else
          __hip_atomic_store(&fC[((unsigned)ib * 32 + (lane - 32)) * 32 + jn], val, AQ, SC);
      }
    }
  }
}

__global__ __launch_bounds__(256, 2) void lstm_fused(
    const float* __restrict__ x,
    const u16* __restrict__ wih0, const u16* __restrict__ whh0, const float* __restrict__ b0,
    const u16* __restrict__ wih1, const u16* __restrict__ whh1, const float* __restrict__ b1,
    unsigned* __restrict__ hx1, u16* __restrict__ h1ring,
    const float* __restrict__ Wfc, float* __restrict__ out,
    unsigned* __restrict__ f0, unsigned* __restrict__ f1, unsigned* __restrict__ f2,
    unsigned* __restrict__ f3)
{
  __shared__ __align__(16) float Gp_s[2 * 64 * 132];
  __shared__ unsigned done_s[4];
  if (threadIdx.x < 4) done_s[threadIdx.x] = 0u;
  __syncthreads();
  const int bx = blockIdx.x;
  // XCD clustering: clique ib lives on XCD bx%8 == ib (both layers)
  if (bx < 256)
    lstm_body<true>(bx & 7, bx >> 3, x, wih0, whh0, b0, (unsigned*)nullptr, h1ring,
                    (const float*)nullptr, (float*)nullptr, f0, f1, f3, Gp_s, done_s);
  else
    lstm_body<false>((bx - 256) & 7, (bx - 256) >> 3, (const float*)nullptr, wih1, whh1, b1,
                     hx1, h1ring, Wfc, out, f2, f1, f3, Gp_s, done_s);
}

extern "C" void kernel_launch(void* const* d_in, const int* in_sizes, int n_in,
                              void* d_out, int out_size, void* d_ws, size_t ws_size,
                              hipStream_t stream) {
  if (ws_size < (size_t)WS_NEEDED) return;

  const float* x    = (const float*)d_in[0];
  const float* Wih0 = (const float*)d_in[1];
  const float* Whh0 = (const float*)d_in[2];
  const float* bih0 = (const float*)d_in[3];
  const float* bhh0 = (const float*)d_in[4];
  const float* Wih1 = (const float*)d_in[5];
  const float* Whh1 = (const float*)d_in[6];
  const float* bih1 = (const float*)d_in[7];
  const float* bhh1 = (const float*)d_in[8];
  const float* Wfc  = (const float*)d_in[9];
  const float* bfc  = (const float*)d_in[10];

  char* ws = (char*)d_ws;
  unsigned* f0   = (unsigned*)(ws + OFF_F0);
  unsigned* f1   = (unsigned*)(ws + OFF_F1);
  unsigned* f2   = (unsigned*)(ws + OFF_F2);
  unsigned* f3   = (unsigned*)(ws + OFF_F3);
  float* b0      = (float*)(ws + OFF_B0);
  float* b1      = (float*)(ws + OFF_B1);
  u16* wih0b     = (u16*)(ws + OFF_WIH0);
  u16* whh0b     = (u16*)(ws + OFF_WHH0);
  u16* wih1b     = (u16*)(ws + OFF_WIH1);
  u16* whh1b     = (u16*)(ws + OFF_WHH1);
  unsigned* hx1  = (unsigned*)(ws + OFF_HX1);
  u16* h1ring    = (u16*)(ws + OFF_H1R);
  float* out     = (float*)d_out;

  prep_kernel<<<12948, 256, 0, stream>>>(Wih0, Whh0, bih0, bhh0, Wih1, Whh1, bih1, bhh1,
                                         bfc, out, ws);

  lstm_fused<<<512, 256, 0, stream>>>(x, wih0b, whh0b, b0, wih1b, whh1b, b1,
                                      hx1, h1ring, Wfc, out, f0, f1, f2, f3);
}

// Round 8
// 2360.742 us; speedup vs baseline: 1.1861x; 1.1861x over previous
//
#include <hip/hip_runtime.h>

typedef unsigned short u16;
typedef unsigned long long u64;
typedef short bf16x8 __attribute__((ext_vector_type(8)));
typedef float f32x4 __attribute__((ext_vector_type(4)));

#define B_ 256
#define T_ 512
#define I_ 64
#define H_ 512
#define RING 32

// ---------------- ws layout (bytes) ---------------- (identical to R4/R6)
#define OFF_F0    0u
#define OFF_F1    32768u
#define OFF_F2    65536u
#define OFF_F3    98304u
#define OFF_B0    131072u
#define OFF_B1    139264u
#define OFF_WIH0  147456u
#define OFF_WHH0  409600u
#define OFF_WIH1  2506752u
#define OFF_WHH1  4603904u
#define OFF_HX1   6701056u
#define OFF_H1R   7225344u
#define WS_NEEDED 15613952u

#define AQ __ATOMIC_RELAXED
#define SC __HIP_MEMORY_SCOPE_AGENT

static __device__ __forceinline__ u16 f2b(float f) {
  union { float f; unsigned u; } v; v.f = f;
  unsigned r = (v.u + 0x7FFFu + ((v.u >> 16) & 1u)) >> 16;
  return (u16)r;
}
static __device__ __forceinline__ float sigm(float x) { return 1.f / (1.f + __expf(-x)); }
static __device__ __forceinline__ float tanh_(float x) { return 1.f - 2.f / (__expf(2.f * x) + 1.f); }

// pipelined spin: 2 outstanding flag loads -> sampling period ~RTT/2
static __device__ __forceinline__ void spin2(const unsigned* __restrict__ pa, unsigned tg) {
  unsigned a = __hip_atomic_load(pa, AQ, SC);
  for (;;) {
    unsigned b = __hip_atomic_load(pa, AQ, SC);
    if (!__any(a < tg)) break;
    a = __hip_atomic_load(pa, AQ, SC);
    if (!__any(b < tg)) break;
  }
}

// ---------------- prep: bf16 weights, bias sums, flag zero, out=bfc ----------------
__global__ void prep_kernel(const float* __restrict__ Wih0, const float* __restrict__ Whh0,
                            const float* __restrict__ bih0, const float* __restrict__ bhh0,
                            const float* __restrict__ Wih1, const float* __restrict__ Whh1,
                            const float* __restrict__ bih1, const float* __restrict__ bhh1,
                            const float* __restrict__ bfc, float* __restrict__ out,
                            char* __restrict__ ws) {
  unsigned* flags = (unsigned*)(ws + OFF_F0);
  float* b0 = (float*)(ws + OFF_B0);
  float* b1 = (float*)(ws + OFF_B1);
  u16* wih0b = (u16*)(ws + OFF_WIH0);
  u16* whh0b = (u16*)(ws + OFF_WHH0);
  u16* wih1b = (u16*)(ws + OFF_WIH1);
  u16* whh1b = (u16*)(ws + OFF_WHH1);

  long long i = (long long)blockIdx.x * 256 + threadIdx.x;
  if (i < 32768) { __hip_atomic_store(&flags[i], 0u, AQ, SC); return; }
  i -= 32768;
  if (i < 256) { out[i] = bfc[0]; return; }
  i -= 256;
  if (i < 2048) { b0[i] = bih0[i] + bhh0[i]; return; }
  i -= 2048;
  if (i < 2048) { b1[i] = bih1[i] + bhh1[i]; return; }
  i -= 2048;
  if (i < 131072) { wih0b[i] = f2b(Wih0[i]); return; }
  i -= 131072;
  if (i < 1048576) { whh0b[i] = f2b(Whh0[i]); return; }
  i -= 1048576;
  if (i < 1048576) { wih1b[i] = f2b(Wih1[i]); return; }
  i -= 1048576;
  if (i < 1048576) { whh1b[i] = f2b(Whh1[i]); return; }
}

// ---------------- fused 2-layer pipelined LSTM (R6 protocol + XCD clustering) --------
// XCD clustering: bx -> (ib = bx&7, jn = bx>>3) so the whole clique for batch-group ib
// (32 L0 + 32 L1 blocks, its flag lines + ring/hx rows) lands on XCD bx%8 = ib.
// Per step (EXACT R6 protocol): [input GEMM] -> wave0 dual-spin -> barA -> setprio1 ->
// rec GEMM -> vec dump (col-major Gp, single buffer) -> barB -> elemwise + h store ->
// setprio0 -> barC (drain) -> wave0 block-granular signal.
template <bool IS_L0>
__device__ __forceinline__ void lstm_body(
    int ib, int jn,
    const float* __restrict__ x,
    const u16* __restrict__ Wib,
    const u16* __restrict__ Whb,
    const float* __restrict__ bias,
    unsigned* __restrict__ hx32,
    u16* __restrict__ h1ring,
    const float* __restrict__ Wfc, float* __restrict__ out,
    unsigned* __restrict__ fR,
    unsigned* __restrict__ fP,
    unsigned* __restrict__ fC,
    float* __restrict__ Gp_s)         // [64 cols][132 rows] f32 (col-major, padded)
{
  const int tid = threadIdx.x;
  const int wv = tid >> 6;
  const int lane = tid & 63;
  const int quad = lane >> 4;
  const int l15 = lane & 15;

  bf16x8 Bh[4][4];
#pragma unroll
  for (int r = 0; r < 4; ++r)
#pragma unroll
    for (int nt = 0; nt < 4; ++nt)
      Bh[r][nt] = *(const bf16x8*)&Whb[(size_t)(nt * 512 + jn * 16 + l15) * 512 +
                                       (wv * 4 + r) * 32 + quad * 8];
  bf16x8 Bx[4][4];
  bf16x8 Bx0[4];
  if constexpr (IS_L0) {
    if (wv < 2) {
#pragma unroll
      for (int nt = 0; nt < 4; ++nt)
        Bx0[nt] = *(const bf16x8*)&Wib[(size_t)(nt * 512 + jn * 16 + l15) * 64 +
                                       wv * 32 + quad * 8];
    }
  } else {
#pragma unroll
    for (int r = 0; r < 4; ++r)
#pragma unroll
      for (int nt = 0; nt < 4; ++nt)
        Bx[r][nt] = *(const bf16x8*)&Wib[(size_t)(nt * 512 + jn * 16 + l15) * 512 +
                                         (wv * 4 + r) * 32 + quad * 8];
  }

  const int erow = tid >> 3;
  const int ecp = tid & 7;
  float bias2[4][2];
#pragma unroll
  for (int g = 0; g < 4; ++g) {
    bias2[g][0] = bias[g * 512 + jn * 16 + 2 * ecp];
    bias2[g][1] = bias[g * 512 + jn * 16 + 2 * ecp + 1];
  }
  float cst2[2] = {0.f, 0.f};
  const f32x4 zf = {0.f, 0.f, 0.f, 0.f};
  const unsigned lineoff = ((unsigned)ib * 32 + jn) * 32;

  const int bg = ib * 32 + erow;
  const int hg = jn * 16 + 2 * ecp;
  const unsigned stoff = (unsigned)(((hg >> 3) * 256 + bg) * 4 + (ecp & 3));

  const unsigned* pollP;
  if constexpr (IS_L0)
    pollP = (lane < 32) ? &fR[lineoff + lane] : &fC[lineoff + (lane - 32)];
  else
    pollP = (lane < 32) ? &fR[lineoff + lane] : &fP[lineoff + (lane - 32)];

  if constexpr (!IS_L0) {
    // pre-loop: confirm fP >= 1 so iteration 0's input GEMM may read ring slot 0
    if (wv == 0) spin2(&fP[lineoff + (lane & 31)], 1u);
    __syncthreads();
  }

  for (int t = 0; t < T_; ++t) {
    f32x4 acc[2][4];
#pragma unroll
    for (int mt = 0; mt < 2; ++mt)
#pragma unroll
      for (int nt = 0; nt < 4; ++nt) acc[mt][nt] = zf;

    if constexpr (IS_L0) {
      // x(t) -> regs; input GEMM before the poll (h-independent)
      if (wv < 2) {
        const float* xp = x + ((size_t)(ib * 32 + l15) * T_ + t) * 64 + wv * 32 + quad * 8;
        const float* xq = xp + (size_t)16 * T_ * 64;
        float4 xa = *(const float4*)xp;
        float4 xb = *(const float4*)(xp + 4);
        float4 xc = *(const float4*)xq;
        float4 xd = *(const float4*)(xq + 4);
        union { unsigned u[4]; bf16x8 v; } P0, P1;
        P0.u[0] = (unsigned)f2b(xa.x) | ((unsigned)f2b(xa.y) << 16);
        P0.u[1] = (unsigned)f2b(xa.z) | ((unsigned)f2b(xa.w) << 16);
        P0.u[2] = (unsigned)f2b(xb.x) | ((unsigned)f2b(xb.y) << 16);
        P0.u[3] = (unsigned)f2b(xb.z) | ((unsigned)f2b(xb.w) << 16);
        P1.u[0] = (unsigned)f2b(xc.x) | ((unsigned)f2b(xc.y) << 16);
        P1.u[1] = (unsigned)f2b(xc.z) | ((unsigned)f2b(xc.w) << 16);
        P1.u[2] = (unsigned)f2b(xd.x) | ((unsigned)f2b(xd.y) << 16);
        P1.u[3] = (unsigned)f2b(xd.z) | ((unsigned)f2b(xd.w) << 16);
#pragma unroll
        for (int nt = 0; nt < 4; ++nt) {
          acc[0][nt] = __builtin_amdgcn_mfma_f32_16x16x32_bf16(P0.v, Bx0[nt], acc[0][nt], 0, 0, 0);
          acc[1][nt] = __builtin_amdgcn_mfma_f32_16x16x32_bf16(P1.v, Bx0[nt], acc[1][nt], 0, 0, 0);
        }
      }
      // wave0 dual-spin: fR >= t ; fC >= t-RING+1
      if (t && wv == 0) {
        const unsigned tg = (lane < 32) ? (unsigned)t
                            : ((t >= RING) ? (unsigned)(t - RING + 1) : 0u);
        spin2(pollP, tg);
      }
      __syncthreads();   // barA
    } else {
      // input GEMM from ring slot t (validity: fP>=t+1 confirmed by prev iter's spin)
      const u64* hq1 = (const u64*)h1ring + (size_t)(t & (RING - 1)) * (B_ * H_ / 4);
#pragma unroll
      for (int r = 0; r < 4; ++r) {
        int ks = wv * 4 + r;
        bf16x8 af[2];
#pragma unroll
        for (int mt = 0; mt < 2; ++mt) {
          const u64* p = hq1 + (size_t)((ks * 4 + quad) * 256 + ib * 32 + mt * 16 + l15) * 2;
          union { u64 q[2]; bf16x8 v; } u;
          u.q[0] = __hip_atomic_load(p, AQ, SC);
          u.q[1] = __hip_atomic_load(p + 1, AQ, SC);
          af[mt] = u.v;
        }
#pragma unroll
        for (int nt = 0; nt < 4; ++nt) {
          acc[0][nt] = __builtin_amdgcn_mfma_f32_16x16x32_bf16(af[0], Bx[r][nt], acc[0][nt], 0, 0, 0);
          acc[1][nt] = __builtin_amdgcn_mfma_f32_16x16x32_bf16(af[1], Bx[r][nt], acc[1][nt], 0, 0, 0);
        }
      }
      // wave0 dual-spin: fR >= t ; fP >= min(t+2, T) (prefetch next step's input validity)
      if (wv == 0) {
        unsigned tP = (unsigned)(t + 2); if (tP > (unsigned)T_) tP = (unsigned)T_;
        const unsigned tg = (lane < 32) ? (unsigned)t : tP;
        spin2(pollP, tg);
      }
      __syncthreads();   // barA
    }

    __builtin_amdgcn_s_setprio(1);

    // ---- recurrent GEMM: L0 reads ring slot (t-1)&31, L1 its parity buffer
    if (t) {
      const u64* hq;
      if constexpr (IS_L0)
        hq = (const u64*)h1ring + (size_t)((t - 1) & (RING - 1)) * (B_ * H_ / 4);
      else
        hq = (const u64*)hx32 + (size_t)(t & 1) * (B_ * H_ / 4);
      bf16x8 af[4][2];
#pragma unroll
      for (int r = 0; r < 4; ++r) {
        int ks = wv * 4 + r;
#pragma unroll
        for (int mt = 0; mt < 2; ++mt) {
          const u64* p = hq + (size_t)((ks * 4 + quad) * 256 + ib * 32 + mt * 16 + l15) * 2;
          union { u64 q[2]; bf16x8 v; } u;
          u.q[0] = __hip_atomic_load(p, AQ, SC);
          u.q[1] = __hip_atomic_load(p + 1, AQ, SC);
          af[r][mt] = u.v;
        }
      }
#pragma unroll
      for (int r = 0; r < 4; ++r)
#pragma unroll
        for (int mt = 0; mt < 2; ++mt)
#pragma unroll
          for (int nt = 0; nt < 4; ++nt)
            acc[mt][nt] = __builtin_amdgcn_mfma_f32_16x16x32_bf16(af[r][mt], Bh[r][nt],
                                                                  acc[mt][nt], 0, 0, 0);
    }

    // ---- vectorized dump, col-major Gp[64 cols][132 rows]: ds_write_b128
#pragma unroll
    for (int mt = 0; mt < 2; ++mt)
#pragma unroll
      for (int nt = 0; nt < 4; ++nt)
        *(f32x4*)&Gp_s[(nt * 16 + l15) * 132 + wv * 32 + mt * 16 + quad * 4] = acc[mt][nt];
    __syncthreads();   // barB

    // ---- elemwise: reduce partials (col-major reads), gates, c/h, store h
    {
      float pre[4][2];
#pragma unroll
      for (int g = 0; g < 4; ++g) {
#pragma unroll
        for (int j = 0; j < 2; ++j) {
          const int c = g * 16 + 2 * ecp + j;
          float s = bias2[g][j];
#pragma unroll
          for (int w = 0; w < 4; ++w) s += Gp_s[c * 132 + w * 32 + erow];
          pre[g][j] = s;
        }
      }
      float hv[2];
#pragma unroll
      for (int j = 0; j < 2; ++j) {
        float iv = sigm(pre[0][j]);
        float fv = sigm(pre[1][j]);
        float gv = tanh_(pre[2][j]);
        float ov = sigm(pre[3][j]);
        float cn = fv * cst2[j] + iv * gv;
        cst2[j] = cn;
        hv[j] = ov * tanh_(cn);
      }
      unsigned pack = (unsigned)f2b(hv[0]) | ((unsigned)f2b(hv[1]) << 16);
      if constexpr (IS_L0) {
        unsigned* ring32 = (unsigned*)h1ring;
        __hip_atomic_store(&ring32[(size_t)(t & (RING - 1)) * (B_ * H_ / 2) + stoff],
                           pack, AQ, SC);
      } else {
        __hip_atomic_store(&hx32[(size_t)((t + 1) & 1) * (B_ * H_ / 2) + stoff], pack, AQ, SC);
        if (t == T_ - 1) {
          float part = hv[0] * Wfc[hg] + hv[1] * Wfc[hg + 1];
          part += __shfl_down(part, 4, 8);
          part += __shfl_down(part, 2, 8);
          part += __shfl_down(part, 1, 8);
          if (ecp == 0) atomicAdd(&out[bg], part);
        }
      }
    }
    __builtin_amdgcn_s_setprio(0);

    // ---- barC drains all waves' h stores (syncthreads implies vmcnt(0)), then signal
    __syncthreads();
    if (wv == 0) {
      unsigned val = (unsigned)(t + 1);
      if constexpr (IS_L0) {
        if (lane < 32)
          __hip_atomic_store(&fR[((unsigned)ib * 32 + lane) * 32 + jn], val, AQ, SC);
        else
          __hip_atomic_store(&fP[((unsigned)ib * 32 + (lane - 32)) * 32 + jn], val, AQ, SC);
      } else {
        if (lane < 32)
          __hip_atomic_store(&fR[((unsigned)ib * 32 + lane) * 32 + jn], val, AQ, SC);
        else
          __hip_atomic_store(&fC[((unsigned)ib * 32 + (lane - 32)) * 32 + jn], val, AQ, SC);
      }
    }
  }
}

__global__ __launch_bounds__(256, 2) void lstm_fused(
    const float* __restrict__ x,
    const u16* __restrict__ wih0, const u16* __restrict__ whh0, const float* __restrict__ b0,
    const u16* __restrict__ wih1, const u16* __restrict__ whh1, const float* __restrict__ b1,
    unsigned* __restrict__ hx1, u16* __restrict__ h1ring,
    const float* __restrict__ Wfc, float* __restrict__ out,
    unsigned* __restrict__ f0, unsigned* __restrict__ f1, unsigned* __restrict__ f2,
    unsigned* __restrict__ f3)
{
  __shared__ __align__(16) float Gp_s[64 * 132];
  const int bx = blockIdx.x;
  // XCD clustering: clique ib lives on XCD bx%8 == ib (both layers)
  if (bx < 256)
    lstm_body<true>(bx & 7, bx >> 3, x, wih0, whh0, b0, (unsigned*)nullptr, h1ring,
                    (const float*)nullptr, (float*)nullptr, f0, f1, f3, Gp_s);
  else
    lstm_body<false>((bx - 256) & 7, (bx - 256) >> 3, (const float*)nullptr, wih1, whh1, b1,
                     hx1, h1ring, Wfc, out, f2, f1, f3, Gp_s);
}

extern "C" void kernel_launch(void* const* d_in, const int* in_sizes, int n_in,
                              void* d_out, int out_size, void* d_ws, size_t ws_size,
                              hipStream_t stream) {
  if (ws_size < (size_t)WS_NEEDED) return;

  const float* x    = (const float*)d_in[0];
  const float* Wih0 = (const float*)d_in[1];
  const float* Whh0 = (const float*)d_in[2];
  const float* bih0 = (const float*)d_in[3];
  const float* bhh0 = (const float*)d_in[4];
  const float* Wih1 = (const float*)d_in[5];
  const float* Whh1 = (const float*)d_in[6];
  const float* bih1 = (const float*)d_in[7];
  const float* bhh1 = (const float*)d_in[8];
  const float* Wfc  = (const float*)d_in[9];
  const float* bfc  = (const float*)d_in[10];

  char* ws = (char*)d_ws;
  unsigned* f0   = (unsigned*)(ws + OFF_F0);
  unsigned* f1   = (unsigned*)(ws + OFF_F1);
  unsigned* f2   = (unsigned*)(ws + OFF_F2);
  unsigned* f3   = (unsigned*)(ws + OFF_F3);
  float* b0      = (float*)(ws + OFF_B0);
  float* b1      = (float*)(ws + OFF_B1);
  u16* wih0b     = (u16*)(ws + OFF_WIH0);
  u16* whh0b     = (u16*)(ws + OFF_WHH0);
  u16* wih1b     = (u16*)(ws + OFF_WIH1);
  u16* whh1b     = (u16*)(ws + OFF_WHH1);
  unsigned* hx1  = (unsigned*)(ws + OFF_HX1);
  u16* h1ring    = (u16*)(ws + OFF_H1R);
  float* out     = (float*)d_out;

  prep_kernel<<<12948, 256, 0, stream>>>(Wih0, Whh0, bih0, bhh0, Wih1, Whh1, bih1, bhh1,
                                         bfc, out, ws);

  lstm_fused<<<512, 256, 0, stream>>>(x, wih0b, whh0b, b0, wih1b, whh1b, b1,
                                      hx1, h1ring, Wfc, out, f0, f1, f2, f3);
}